// Round 16
// baseline (79.563 us; speedup 1.0000x reference)
//
#include <hip/hip_runtime.h>

#define HW 6144
#define HH 64
#define WWID 96

typedef __attribute__((ext_vector_type(8))) _Float16 half8;
typedef __attribute__((ext_vector_type(2))) _Float16 half2v;
typedef __attribute__((ext_vector_type(8))) unsigned short ushort8;
typedef __attribute__((ext_vector_type(4))) float floatx4;
typedef __attribute__((ext_vector_type(4))) uint uint4v;
typedef __attribute__((ext_vector_type(4))) int int4v;

static __device__ __forceinline__ ushort f2h(float x) {
  _Float16 h = (_Float16)x;
  return __builtin_bit_cast(ushort, h);
}
static __device__ __forceinline__ float h2f(ushort b) {
  return (float)__builtin_bit_cast(_Float16, b);
}
static __device__ __forceinline__ uint pk2h(float a, float b) {
  return __builtin_bit_cast(uint, __builtin_amdgcn_cvt_pkrtz(a, b));
}
static __device__ __forceinline__ float hdot2(uint a, uint b, float c) {
#if __has_builtin(__builtin_amdgcn_fdot2)
  return __builtin_amdgcn_fdot2(__builtin_bit_cast(half2v, a),
                                __builtin_bit_cast(half2v, b), c, false);
#else
  c = fmaf(h2f((ushort)a), h2f((ushort)b), c);
  return fmaf(h2f((ushort)(a >> 16)), h2f((ushort)(b >> 16)), c);
#endif
}
static __device__ __forceinline__ half2v h2shfl(half2v v, int d) {
  return __builtin_bit_cast(half2v,
      (uint)__shfl_xor((int)__builtin_bit_cast(uint, v), d));
}
static __device__ __forceinline__ half8 h8scale(half8 a, _Float16 s) {
  half8 r;
#pragma unroll
  for (int j = 0; j < 8; ++j) r[j] = a[j] * s;
  return r;
}

// ---------------- conv1x1 + relu via MFMA (W fp32 -> frags in-register) ----------------
// Grid 1536 = 8 b x 192 p-tiles(32). Block 0 zeroes the 128-byte OOB sink row of each Y.
__global__ __launch_bounds__(256) void conv_mfma_kernel(
    const float* __restrict__ X, const float* __restrict__ W1,
    const float* __restrict__ W2, const float* __restrict__ W3,
    ushort* __restrict__ Y1, ushort* __restrict__ Y2, ushort* __restrict__ Y3) {
  __shared__ __align__(16) ushort Xt[32 * 72];  // [p][c^], XOR-swizzled fp16
  const int tid = threadIdx.x;
  const int wid = tid >> 6, lane = tid & 63;
  const int b = blockIdx.x / 192;
  const int p0 = (blockIdx.x % 192) * 32;

  if (blockIdx.x == 0 && tid < 96) {  // zero sinks for attn's OOB loads
    int which = tid >> 5, i = tid & 31;
    ushort* Ys = which == 0 ? Y1 : which == 1 ? Y2 : Y3;
    ((uint*)(Ys + (size_t)8 * HW * 64))[i] = 0u;
  }

#pragma unroll
  for (int it = 0; it < 2; ++it) {
    int idx = it * 256 + tid;
    int c = idx >> 3, pq = idx & 7;
    floatx4 v = *(const floatx4*)&X[((size_t)b * 64 + c) * HW + p0 + 4 * pq];
#pragma unroll
    for (int j = 0; j < 4; ++j) {
      int p = 4 * pq + j;
      Xt[p * 72 + (c ^ (p & 56))] = f2h(v[j]);
    }
  }
  __syncthreads();

  const int col = lane & 15, kg = lane >> 4;
  const int ph = wid & 1, mth = wid >> 1;
  const int p = ph * 16 + col;
  half8 b0 = *(const half8*)&Xt[p * 72 + ((kg * 8) ^ (p & 56))];
  half8 b1 = *(const half8*)&Xt[p * 72 + ((kg * 8 + 32) ^ (p & 56))];
  const size_t pixbase = ((size_t)b * HW + p0 + p) * 64;

  for (int s = 0; s < 3; ++s) {
    const float* Wf = (s == 0) ? W1 : (s == 1) ? W2 : W3;
    ushort* Y = (s == 0) ? Y1 : (s == 1) ? Y2 : Y3;
#pragma unroll
    for (int m = 0; m < 2; ++m) {
      int mt = mth * 2 + m;
      const float* wp = &Wf[(mt * 16 + col) * 64 + kg * 8];
      floatx4 w0 = *(const floatx4*)wp;
      floatx4 w1v = *(const floatx4*)(wp + 4);
      floatx4 w2v = *(const floatx4*)(wp + 32);
      floatx4 w3v = *(const floatx4*)(wp + 36);
      uint4v ua, ub;
      ua[0] = pk2h(w0[0], w0[1]);  ua[1] = pk2h(w0[2], w0[3]);
      ua[2] = pk2h(w1v[0], w1v[1]); ua[3] = pk2h(w1v[2], w1v[3]);
      ub[0] = pk2h(w2v[0], w2v[1]); ub[1] = pk2h(w2v[2], w2v[3]);
      ub[2] = pk2h(w3v[0], w3v[1]); ub[3] = pk2h(w3v[2], w3v[3]);
      half8 a0 = __builtin_bit_cast(half8, ua);
      half8 a1 = __builtin_bit_cast(half8, ub);
      floatx4 acc = {0.f, 0.f, 0.f, 0.f};
      acc = __builtin_amdgcn_mfma_f32_16x16x32_f16(a0, b0, acc, 0, 0, 0);
      acc = __builtin_amdgcn_mfma_f32_16x16x32_f16(a1, b1, acc, 0, 0, 0);
      uint2 u;
      u.x = pk2h(fmaxf(acc[0], 0.f), fmaxf(acc[1], 0.f));
      u.y = pk2h(fmaxf(acc[2], 0.f), fmaxf(acc[3], 0.f));
      *(uint2*)&Y[pixbase + mt * 16 + 4 * kg] = u;
    }
  }
}

// ---------------- per-pixel attention stage ----------------
// 12288 blocks x 256. LDS 23040 B -> 7 blocks/CU.
__global__ __launch_bounds__(256, 7) void attn_kernel(
    const ushort* __restrict__ Y1, const ushort* __restrict__ Y2,
    const ushort* __restrict__ Y3, float* __restrict__ out) {
  __shared__ __align__(16) ushort XS[2 * 48 * 72];  // X1b, X2b fp16; X6f fp32 overlay later
  __shared__ __align__(16) ushort P1b[48 * 72];     // P' fp16; cols 48..63 zero; 64..71 scratch
  __shared__ __align__(16) uint mmv[2][128];        // half2-packed means; later expL4 (P6..P8)
  __shared__ __align__(16) uint vvv[2][128];        // half2-packed vars; later SS3/SS2/Mm

  ushort* X1b = XS;
  ushort* X2b = XS + 48 * 72;
  float* X6f = (float*)XS;       // 36 x 68 fp32, valid after X1b/X2b dead
  float* SSf = (float*)vvv;      // [0..15]=SS3 [16..31]=SS2 [32..47]=Mm (valid in/after P1)
  float* L4f = (float*)mmv;      // [0..35] exp(score4 logits) (valid P6..P8)

  const int tid = threadIdx.x;
  const int wid = tid >> 6;
  const int lane = tid & 63;
  const int bid0 = blockIdx.x;
  const int bid = (bid0 & 7) * (12288 >> 3) + (bid0 >> 3);  // XCD-bijective
  const int pix = bid % HW;
  const int nn = bid / HW;
  const int h = pix / WWID, w = pix - h * WWID;
  const int tb0 = nn * 4;
  const int SINKE = 8 * HW * 64;  // element offset of zero sink row in each Y

  // ---- P0: uint4 tap loads (sink-redirected) + packed-fp16 stats; offv; pads ----
  {
    const int s = wid >> 1;                      // tensor (0=Y1, 1=Y2)
    const int t = (wid & 1) * 2 + (lane >> 5);   // 2 t's per wave
    const int l32 = lane & 31;
    const int c8 = l32 & 7;                      // c-octet
    const int kq = l32 >> 3;                     // 0..3
    const ushort* Ysrc = s ? Y2 : Y1;
    const int base = (tb0 + t) * HW + pix;
    half2v s1[4] = {{0, 0}, {0, 0}, {0, 0}, {0, 0}};
    half2v s2[4] = {{0, 0}, {0, 0}, {0, 0}, {0, 0}};
#pragma unroll
    for (int it = 0; it < 3; ++it) {
      int k = it * 4 + kq;
      if (k < 9) {
        int k3 = (k * 11) >> 5;
        int dh = k3 - 1, dw = k - 3 * k3 - 1;
        bool valid = ((unsigned)(h + dh) < HH) & ((unsigned)(w + dw) < WWID);
        int off = valid ? (base + dh * WWID + dw) * 64 : SINKE;
        uint4v uv = *(const uint4v*)&Ysrc[off + 8 * c8];
        *(uint4v*)&XS[s * 3456 + (t * 9 + k) * 72 + 8 * c8] = uv;
#pragma unroll
        for (int q = 0; q < 4; ++q) {
          half2v v = __builtin_bit_cast(half2v, uv[q]);
          s1[q] += v;
          s2[q] += v * v;
        }
      }
    }
#pragma unroll
    for (int q = 0; q < 4; ++q) {
      s1[q] += h2shfl(s1[q], 8);
      s2[q] += h2shfl(s2[q], 8);
      s1[q] += h2shfl(s1[q], 16);
      s2[q] += h2shfl(s2[q], 16);
    }
    if (kq == 0) {
#pragma unroll
      for (int q = 0; q < 4; ++q) {
        float a0 = (float)s1[q][0], a1 = (float)s1[q][1];
        float q0 = (float)s2[q][0], q1 = (float)s2[q][1];
        float m0 = a0 * (1.f / 9.f), m1 = a1 * (1.f / 9.f);
        float v0 = (q0 - a0 * a0 * (1.f / 9.f)) * 0.125f;
        float v1 = (q1 - a1 * a1 * (1.f / 9.f)) * 0.125f;
        mmv[s][t * 32 + c8 * 4 + q] = pk2h(m0, m1);
        vvv[s][t * 32 + c8 * 4 + q] = pk2h(v0, v1);
      }
    }
  }
  if (tid < 64) {  // offv: BYTE offset of (t,tap) pixel row in Y3 (sink if OOB/pad)
    int b = tid;
    int o = SINKE * 2;
    if (b < 36) {
      int t = (b * 57) >> 9;
      int k = b - 9 * t;
      int k3 = (k * 11) >> 5;
      int hh = h + k3 - 1, ww = w + (k - 3 * k3) - 1;
      if ((unsigned)hh < HH && (unsigned)ww < WWID)
        o = ((tb0 + t) * HW + hh * WWID + ww) * 128;
    }
    ((int*)&P1b[(b >> 2) * 72 + 64])[b & 3] = o;
  }
  for (int i = tid; i < 384; i += 256) {  // P1b K-pad cols 48..63 (finite)
    int r = i >> 3, u = i & 7;
    *(uint*)&P1b[r * 72 + 48 + 2 * u] = 0u;
  }
  for (int i = tid; i < 192; i += 256) {  // X2b pad rows 36..47
    int r = i >> 4, cq = i & 15;
    uint2 z; z.x = 0u; z.y = 0u;
    *(uint2*)&X2b[(36 + r) * 72 + 4 * cq] = z;
  }
  __syncthreads();

  // ---- X3 B-frags: int4-packed offsets + unconditional gather (drains under P1) ----
  const int colL = lane & 15, kg = lane >> 4;
  ushort8 xv0, xv1;
  {
    const int c2 = (wid * 16 + colL) * 2;
    const char* Y3b = (const char*)Y3;
    int4v oa = *(const int4v*)&P1b[(kg * 2) * 72 + 64];
    int4v ob = *(const int4v*)&P1b[(kg * 2 + 1) * 72 + 64];
    int4v oc = *(const int4v*)&P1b[(kg * 2 + 8) * 72 + 64];
    int4v od = *(const int4v*)&P1b[(kg * 2 + 9) * 72 + 64];
#pragma unroll
    for (int j = 0; j < 4; ++j) {
      xv0[j] = *(const ushort*)(Y3b + (oa[j] + c2));
      xv0[4 + j] = *(const ushort*)(Y3b + (ob[j] + c2));
      xv1[j] = *(const ushort*)(Y3b + (oc[j] + c2));
      xv1[4 + j] = *(const ushort*)(Y3b + (od[j] + c2));
    }
  }

  // ---- P1: S1 MFMA (log2e-scaled A) + exp2 softmax + P' (waves 0-2) || dots (wave 3) ----
  if (wid < 3) {
    floatx4 ac0 = {0.f, 0.f, 0.f, 0.f}, ac1 = ac0, ac2 = ac0;
    int ar = (wid * 16 + colL) * 72 + (kg << 3);
    half8 a0 = h8scale(*(const half8*)&X1b[ar], (_Float16)1.442695f);
    half8 a1 = h8scale(*(const half8*)&X1b[ar + 32], (_Float16)1.442695f);
    int brb = colL * 72 + (kg << 3);
    ac0 = __builtin_amdgcn_mfma_f32_16x16x32_f16(a0, *(const half8*)&X2b[brb], ac0, 0, 0, 0);
    ac0 = __builtin_amdgcn_mfma_f32_16x16x32_f16(a1, *(const half8*)&X2b[brb + 32], ac0, 0, 0, 0);
    ac1 = __builtin_amdgcn_mfma_f32_16x16x32_f16(a0, *(const half8*)&X2b[brb + 16 * 72], ac1, 0, 0, 0);
    ac1 = __builtin_amdgcn_mfma_f32_16x16x32_f16(a1, *(const half8*)&X2b[brb + 16 * 72 + 32], ac1, 0, 0, 0);
    ac2 = __builtin_amdgcn_mfma_f32_16x16x32_f16(a0, *(const half8*)&X2b[brb + 32 * 72], ac2, 0, 0, 0);
    ac2 = __builtin_amdgcn_mfma_f32_16x16x32_f16(a1, *(const half8*)&X2b[brb + 32 * 72 + 32], ac2, 0, 0, 0);

    bool v2 = (colL < 4);
#pragma unroll
    for (int r = 0; r < 4; ++r) {
      float e0 = exp2f(ac0[r]);
      float e1 = exp2f(ac1[r]);
      float e2 = exp2f(ac2[r]);
      float sm = e0 + e1 + (v2 ? e2 : 0.f);
#pragma unroll
      for (int d = 1; d < 16; d <<= 1) sm += __shfl_xor(sm, d);
      float rs = __builtin_amdgcn_rcpf(sm);
      int ro = (wid * 16 + 4 * kg + r) * 72 + colL;
      P1b[ro] = f2h(e0 * rs);
      P1b[ro + 16] = f2h(e1 * rs);
      P1b[ro + 32] = f2h(e2 * rs);
    }
  } else {
    int pr = lane >> 2, q = lane & 3;
    int t1 = pr >> 2, t2 = pr & 3;
    float a3 = 0.f, a2 = 0.f;
#pragma unroll
    for (int j = 0; j < 8; ++j) {
      int cp = q * 8 + j;
      a3 = hdot2(mmv[0][t1 * 32 + cp], mmv[1][t2 * 32 + cp], a3);
      a2 = hdot2(vvv[0][t1 * 32 + cp], vvv[1][t2 * 32 + cp], a2);
    }
    a3 += __shfl_xor(a3, 1);
    a3 += __shfl_xor(a3, 2);
    a2 += __shfl_xor(a2, 1);
    a2 += __shfl_xor(a2, 2);
    if (q == 0) { SSf[pr] = a3; SSf[16 + pr] = a2; }  // overlay on vvv: same-wave WAR
    if (lane < 4) {
      floatx4 v3 = *(const floatx4*)&SSf[lane * 4];
      floatx4 v2v = *(const floatx4*)&SSf[16 + lane * 4];
      float e3[4], e2v[4], s3 = 0.f, s2v = 0.f;
#pragma unroll
      for (int j = 0; j < 4; ++j) {
        e3[j] = __expf(v3[j]); s3 += e3[j];
        e2v[j] = __expf(v2v[j]); s2v += e2v[j];
      }
      float r3 = __builtin_amdgcn_rcpf(s3), r2 = __builtin_amdgcn_rcpf(s2v);
      floatx4 mm;
#pragma unroll
      for (int j = 0; j < 4; ++j) mm[j] = fmaf(e3[j], r3, e2v[j] * r2);
      *(floatx4*)&SSf[32 + lane * 4] = mm;
    }
  }
  __syncthreads();  // P' + Mm ready

  // ---- P3: diagonal fold P'[a][tb*9+ka] += Mm[ta][tb] (144 lanes) ----
  if (tid < 144) {
    int a = tid >> 2, t2i = tid & 3;
    int ta = (a * 57) >> 9;
    int ka = a - 9 * ta;
    int off = a * 72 + t2i * 9 + ka;
    P1b[off] = f2h(h2f(P1b[off]) + SSf[32 + ta * 4 + t2i]);
  }
  __syncthreads();

  // ---- P5: x6 = P'' @ X3 via MFMA (wave = c-block; B-frags from gathered regs) ----
  {
    half8 xb0 = __builtin_bit_cast(half8, xv0);
    half8 xb1 = __builtin_bit_cast(half8, xv1);
    int c = wid * 16 + colL;
#pragma unroll
    for (int ti = 0; ti < 3; ++ti) {
      floatx4 acc = {0.f, 0.f, 0.f, 0.f};
      int ar = (ti * 16 + colL) * 72 + (kg << 3);
      acc = __builtin_amdgcn_mfma_f32_16x16x32_f16(*(const half8*)&P1b[ar], xb0, acc, 0, 0, 0);
      acc = __builtin_amdgcn_mfma_f32_16x16x32_f16(*(const half8*)&P1b[ar + 32], xb1, acc, 0, 0, 0);
      int r0 = ti * 16 + (kg << 2);
#pragma unroll
      for (int r = 0; r < 4; ++r) {
        int a = r0 + r;
        if (a < 36) X6f[a * 68 + c] = acc[r];
      }
    }
  }
  __syncthreads();

  // ---- P6: exp'd score4 logits expL[a] = exp(<x6[a,:], x6[ctr,:]>) (144 lanes) ----
  if (tid < 144) {
    int a = tid >> 2, q = tid & 3;
    int ctr = ((a * 57) >> 9) * 9 + 4;
    const floatx4* rowA = (const floatx4*)&X6f[a * 68 + q * 16];
    const floatx4* rowC = (const floatx4*)&X6f[ctr * 68 + q * 16];
    float s = 0.f;
#pragma unroll
    for (int j = 0; j < 4; ++j) {
      floatx4 va = rowA[j], vc = rowC[j];
      s = fmaf(va[0], vc[0], s);
      s = fmaf(va[1], vc[1], s);
      s = fmaf(va[2], vc[2], s);
      s = fmaf(va[3], vc[3], s);
    }
    s += __shfl_xor(s, 1);
    s += __shfl_xor(s, 2);
    if (q == 0) L4f[a] = __expf(s);  // pre-exp'd; overlay on mmv (dead)
  }
  __syncthreads();

  // ---- P8: softmax-pool from pre-exp'd weights (t=wid, c=lane) ----
  {
    float den = 0.f, num = 0.f;
#pragma unroll
    for (int k = 0; k < 9; ++k) {
      float e = L4f[wid * 9 + k];
      den += e;
      num = fmaf(X6f[(wid * 9 + k) * 68 + lane], e, num);
    }
    out[((size_t)(tb0 + wid) * 64 + lane) * HW + pix] = num * __builtin_amdgcn_rcpf(den);
  }
}

extern "C" void kernel_launch(void* const* d_in, const int* in_sizes, int n_in,
                              void* d_out, int out_size, void* d_ws, size_t ws_size,
                              hipStream_t stream) {
  const float* x = (const float*)d_in[0];
  const float* w1 = (const float*)d_in[1];
  const float* w2 = (const float*)d_in[2];
  const float* w3 = (const float*)d_in[3];
  float* out = (float*)d_out;

  size_t ysz = (size_t)8 * HW * 64;   // fp16 elements per tensor
  size_t ypitch = ysz + 64;           // +64-elem (128 B) zero sink row
  ushort* Y1 = (ushort*)d_ws;
  ushort* Y2 = Y1 + ypitch;
  ushort* Y3 = Y2 + ypitch;

  conv_mfma_kernel<<<dim3(1536), dim3(256), 0, stream>>>(x, w1, w2, w3, Y1, Y2, Y3);
  attn_kernel<<<dim3(2 * HW), dim3(256), 0, stream>>>(Y1, Y2, Y3, out);
}

// Round 17
// 73.624 us; speedup vs baseline: 1.0807x; 1.0807x over previous
//
#include <hip/hip_runtime.h>

#define HW 6144
#define HH 64
#define WWID 96

typedef __attribute__((ext_vector_type(8))) _Float16 half8;
typedef __attribute__((ext_vector_type(2))) _Float16 half2v;
typedef __attribute__((ext_vector_type(8))) unsigned short ushort8;
typedef __attribute__((ext_vector_type(4))) float floatx4;
typedef __attribute__((ext_vector_type(4))) uint uint4v;
typedef __attribute__((ext_vector_type(4))) int int4v;

static __device__ __forceinline__ ushort f2h(float x) {
  _Float16 h = (_Float16)x;
  return __builtin_bit_cast(ushort, h);
}
static __device__ __forceinline__ float h2f(ushort b) {
  return (float)__builtin_bit_cast(_Float16, b);
}
static __device__ __forceinline__ uint pk2h(float a, float b) {
  return __builtin_bit_cast(uint, __builtin_amdgcn_cvt_pkrtz(a, b));
}
static __device__ __forceinline__ float hdot2(uint a, uint b, float c) {
#if __has_builtin(__builtin_amdgcn_fdot2)
  return __builtin_amdgcn_fdot2(__builtin_bit_cast(half2v, a),
                                __builtin_bit_cast(half2v, b), c, false);
#else
  c = fmaf(h2f((ushort)a), h2f((ushort)b), c);
  return fmaf(h2f((ushort)(a >> 16)), h2f((ushort)(b >> 16)), c);
#endif
}
static __device__ __forceinline__ half2v h2shfl16(half2v v) {
  return __builtin_bit_cast(half2v,
      (uint)__shfl_xor((int)__builtin_bit_cast(uint, v), 16));
}

// ---------------- conv1x1 + relu via MFMA (W fp32 -> frags in-register) ----------------
// Grid 1536 = 8 b x 192 p-tiles(32). Block 0 zeroes the 128-byte OOB sink row of each Y.
__global__ __launch_bounds__(256) void conv_mfma_kernel(
    const float* __restrict__ X, const float* __restrict__ W1,
    const float* __restrict__ W2, const float* __restrict__ W3,
    ushort* __restrict__ Y1, ushort* __restrict__ Y2, ushort* __restrict__ Y3) {
  __shared__ __align__(16) ushort Xt[32 * 72];  // [p][c^], XOR-swizzled fp16
  const int tid = threadIdx.x;
  const int wid = tid >> 6, lane = tid & 63;
  const int b = blockIdx.x / 192;
  const int p0 = (blockIdx.x % 192) * 32;

  if (blockIdx.x == 0 && tid < 96) {  // zero sinks for attn's OOB loads
    int which = tid >> 5, i = tid & 31;
    ushort* Ys = which == 0 ? Y1 : which == 1 ? Y2 : Y3;
    ((uint*)(Ys + (size_t)8 * HW * 64))[i] = 0u;
  }

#pragma unroll
  for (int it = 0; it < 2; ++it) {
    int idx = it * 256 + tid;
    int c = idx >> 3, pq = idx & 7;
    floatx4 v = *(const floatx4*)&X[((size_t)b * 64 + c) * HW + p0 + 4 * pq];
#pragma unroll
    for (int j = 0; j < 4; ++j) {
      int p = 4 * pq + j;
      Xt[p * 72 + (c ^ (p & 56))] = f2h(v[j]);
    }
  }
  __syncthreads();

  const int col = lane & 15, kg = lane >> 4;
  const int ph = wid & 1, mth = wid >> 1;
  const int p = ph * 16 + col;
  half8 b0 = *(const half8*)&Xt[p * 72 + ((kg * 8) ^ (p & 56))];
  half8 b1 = *(const half8*)&Xt[p * 72 + ((kg * 8 + 32) ^ (p & 56))];
  const size_t pixbase = ((size_t)b * HW + p0 + p) * 64;

  for (int s = 0; s < 3; ++s) {
    const float* Wf = (s == 0) ? W1 : (s == 1) ? W2 : W3;
    ushort* Y = (s == 0) ? Y1 : (s == 1) ? Y2 : Y3;
#pragma unroll
    for (int m = 0; m < 2; ++m) {
      int mt = mth * 2 + m;
      const float* wp = &Wf[(mt * 16 + col) * 64 + kg * 8];
      floatx4 w0 = *(const floatx4*)wp;
      floatx4 w1v = *(const floatx4*)(wp + 4);
      floatx4 w2v = *(const floatx4*)(wp + 32);
      floatx4 w3v = *(const floatx4*)(wp + 36);
      uint4v ua, ub;
      ua[0] = pk2h(w0[0], w0[1]);  ua[1] = pk2h(w0[2], w0[3]);
      ua[2] = pk2h(w1v[0], w1v[1]); ua[3] = pk2h(w1v[2], w1v[3]);
      ub[0] = pk2h(w2v[0], w2v[1]); ub[1] = pk2h(w2v[2], w2v[3]);
      ub[2] = pk2h(w3v[0], w3v[1]); ub[3] = pk2h(w3v[2], w3v[3]);
      half8 a0 = __builtin_bit_cast(half8, ua);
      half8 a1 = __builtin_bit_cast(half8, ub);
      floatx4 acc = {0.f, 0.f, 0.f, 0.f};
      acc = __builtin_amdgcn_mfma_f32_16x16x32_f16(a0, b0, acc, 0, 0, 0);
      acc = __builtin_amdgcn_mfma_f32_16x16x32_f16(a1, b1, acc, 0, 0, 0);
      uint2 u;
      u.x = pk2h(fmaxf(acc[0], 0.f), fmaxf(acc[1], 0.f));
      u.y = pk2h(fmaxf(acc[2], 0.f), fmaxf(acc[3], 0.f));
      *(uint2*)&Y[pixbase + mt * 16 + 4 * kg] = u;
    }
  }
}

// ---------------- per-pixel attention stage ----------------
// 12288 blocks x 256. LDS 22784 B -> 7 blocks/CU.
__global__ __launch_bounds__(256, 7) void attn_kernel(
    const ushort* __restrict__ Y1, const ushort* __restrict__ Y2,
    const ushort* __restrict__ Y3, float* __restrict__ out) {
  __shared__ __align__(16) ushort XS[2 * 48 * 72];  // X1b, X2b fp16; X6f fp32 overlay later
  __shared__ __align__(16) ushort P1b[48 * 72];     // P' fp16; cols 48..63 zero; 64..71 scratch
  __shared__ __align__(16) uint mmv[2][128];        // half2-packed means; later expL4 (P6..P8)
  __shared__ __align__(16) uint vvv[2][128];        // half2-packed vars; later SS3/SS2/Mm

  ushort* X1b = XS;
  ushort* X2b = XS + 48 * 72;
  float* X6f = (float*)XS;       // 36 x 68 fp32, valid after X1b/X2b dead
  float* SSf = (float*)vvv;      // [0..15]=SS3 [16..31]=SS2 [32..47]=Mm (valid in/after P1)
  float* L4f = (float*)mmv;      // [0..35] exp(score4 logits) (valid P6..P8)

  const int tid = threadIdx.x;
  const int wid = tid >> 6;
  const int lane = tid & 63;
  const int bid0 = blockIdx.x;
  const int bid = (bid0 & 7) * (12288 >> 3) + (bid0 >> 3);  // XCD-bijective
  const int pix = bid % HW;
  const int nn = bid / HW;
  const int h = pix / WWID, w = pix - h * WWID;
  const int tb0 = nn * 4;
  const int SINKE = 8 * HW * 64;  // element offset of zero sink row in each Y

  // ---- P0: tap loads (sink-redirected, unconditional) + packed-fp16 stats; offv; pads ----
  {
    const int s = wid >> 1;
    const int t = (wid & 1) * 2 + (lane >> 5);
    const int kh = (lane >> 4) & 1;
    const int cq = lane & 15;
    const ushort* Ysrc = s ? Y2 : Y1;
    const int base = (tb0 + t) * HW + pix;  // element-row index of center pixel
    half2v s1a = {0, 0}, s1b = {0, 0}, s2a = {0, 0}, s2b = {0, 0};
#pragma unroll
    for (int i = 0; i < 5; ++i) {
      int k = 2 * i + kh;
      if (k < 9) {
        int k3 = (k * 11) >> 5;
        int dh = k3 - 1, dw = k - 3 * k3 - 1;
        bool valid = ((unsigned)(h + dh) < HH) & ((unsigned)(w + dw) < WWID);
        int off = valid ? (base + dh * WWID + dw) * 64 : SINKE;
        uint2 uv = *(const uint2*)&Ysrc[off + 4 * cq];
        *(uint2*)&XS[s * 3456 + (t * 9 + k) * 72 + 4 * cq] = uv;
        half2v va = __builtin_bit_cast(half2v, uv.x);
        half2v vb = __builtin_bit_cast(half2v, uv.y);
        s1a += va; s2a += va * va;
        s1b += vb; s2b += vb * vb;
      }
    }
    s1a += h2shfl16(s1a);
    s1b += h2shfl16(s1b);
    s2a += h2shfl16(s2a);
    s2b += h2shfl16(s2b);
    if (kh == 0) {
      float s1f[4] = {(float)s1a[0], (float)s1a[1], (float)s1b[0], (float)s1b[1]};
      float s2f[4] = {(float)s2a[0], (float)s2a[1], (float)s2b[0], (float)s2b[1]};
      float mf[4], vf[4];
#pragma unroll
      for (int j = 0; j < 4; ++j) {
        mf[j] = s1f[j] * (1.f / 9.f);
        vf[j] = (s2f[j] - s1f[j] * s1f[j] * (1.f / 9.f)) * 0.125f;
      }
      mmv[s][t * 32 + 2 * cq] = pk2h(mf[0], mf[1]);
      mmv[s][t * 32 + 2 * cq + 1] = pk2h(mf[2], mf[3]);
      vvv[s][t * 32 + 2 * cq] = pk2h(vf[0], vf[1]);
      vvv[s][t * 32 + 2 * cq + 1] = pk2h(vf[2], vf[3]);
    }
  }
  if (tid < 64) {  // offv: BYTE offset of (t,tap) pixel row in Y3 (sink if OOB/pad)
    int b = tid;
    int o = SINKE * 2;
    if (b < 36) {
      int t = (b * 57) >> 9;
      int k = b - 9 * t;
      int k3 = (k * 11) >> 5;
      int hh = h + k3 - 1, ww = w + (k - 3 * k3) - 1;
      if ((unsigned)hh < HH && (unsigned)ww < WWID)
        o = ((tb0 + t) * HW + hh * WWID + ww) * 128;
    }
    ((int*)&P1b[(b >> 2) * 72 + 64])[b & 3] = o;
  }
  for (int i = tid; i < 384; i += 256) {  // P1b K-pad cols 48..63 (finite)
    int r = i >> 3, u = i & 7;
    *(uint*)&P1b[r * 72 + 48 + 2 * u] = 0u;
  }
  for (int i = tid; i < 192; i += 256) {  // X2b pad rows 36..47
    int r = i >> 4, cq = i & 15;
    uint2 z; z.x = 0u; z.y = 0u;
    *(uint2*)&X2b[(36 + r) * 72 + 4 * cq] = z;
  }
  __syncthreads();

  // ---- X3 B-frags: int4-packed offsets + unconditional gather (drains under P1) ----
  const int colL = lane & 15, kg = lane >> 4;
  ushort8 xv0, xv1;
  {
    const int c2 = (wid * 16 + colL) * 2;
    const char* Y3b = (const char*)Y3;
    int4v oa = *(const int4v*)&P1b[(kg * 2) * 72 + 64];
    int4v ob = *(const int4v*)&P1b[(kg * 2 + 1) * 72 + 64];
    int4v oc = *(const int4v*)&P1b[(kg * 2 + 8) * 72 + 64];
    int4v od = *(const int4v*)&P1b[(kg * 2 + 9) * 72 + 64];
#pragma unroll
    for (int j = 0; j < 4; ++j) {
      xv0[j] = *(const ushort*)(Y3b + (oa[j] + c2));
      xv0[4 + j] = *(const ushort*)(Y3b + (ob[j] + c2));
      xv1[j] = *(const ushort*)(Y3b + (oc[j] + c2));
      xv1[4 + j] = *(const ushort*)(Y3b + (od[j] + c2));
    }
  }

  // ---- P1: S1 MFMA + no-max softmax + P' (waves 0-2) || fdot2 dots + Mm (wave 3) ----
  if (wid < 3) {
    floatx4 ac0 = {0.f, 0.f, 0.f, 0.f}, ac1 = ac0, ac2 = ac0;
    int ar = (wid * 16 + colL) * 72 + (kg << 3);
    half8 a0 = *(const half8*)&X1b[ar];
    half8 a1 = *(const half8*)&X1b[ar + 32];
    int brb = colL * 72 + (kg << 3);
    ac0 = __builtin_amdgcn_mfma_f32_16x16x32_f16(a0, *(const half8*)&X2b[brb], ac0, 0, 0, 0);
    ac0 = __builtin_amdgcn_mfma_f32_16x16x32_f16(a1, *(const half8*)&X2b[brb + 32], ac0, 0, 0, 0);
    ac1 = __builtin_amdgcn_mfma_f32_16x16x32_f16(a0, *(const half8*)&X2b[brb + 16 * 72], ac1, 0, 0, 0);
    ac1 = __builtin_amdgcn_mfma_f32_16x16x32_f16(a1, *(const half8*)&X2b[brb + 16 * 72 + 32], ac1, 0, 0, 0);
    ac2 = __builtin_amdgcn_mfma_f32_16x16x32_f16(a0, *(const half8*)&X2b[brb + 32 * 72], ac2, 0, 0, 0);
    ac2 = __builtin_amdgcn_mfma_f32_16x16x32_f16(a1, *(const half8*)&X2b[brb + 32 * 72 + 32], ac2, 0, 0, 0);

    bool v2 = (colL < 4);
#pragma unroll
    for (int r = 0; r < 4; ++r) {
      float e0 = __expf(ac0[r]);
      float e1 = __expf(ac1[r]);
      float e2 = __expf(ac2[r]);
      float sm = e0 + e1 + (v2 ? e2 : 0.f);
#pragma unroll
      for (int d = 1; d < 16; d <<= 1) sm += __shfl_xor(sm, d);
      float rs = __builtin_amdgcn_rcpf(sm);
      int ro = (wid * 16 + 4 * kg + r) * 72 + colL;
      P1b[ro] = f2h(e0 * rs);
      P1b[ro + 16] = f2h(e1 * rs);
      P1b[ro + 32] = f2h(e2 * rs);
    }
  } else {
    int pr = lane >> 2, q = lane & 3;
    int t1 = pr >> 2, t2 = pr & 3;
    float a3 = 0.f, a2 = 0.f;
#pragma unroll
    for (int j = 0; j < 8; ++j) {
      int cp = q * 8 + j;
      a3 = hdot2(mmv[0][t1 * 32 + cp], mmv[1][t2 * 32 + cp], a3);
      a2 = hdot2(vvv[0][t1 * 32 + cp], vvv[1][t2 * 32 + cp], a2);
    }
    a3 += __shfl_xor(a3, 1);
    a3 += __shfl_xor(a3, 2);
    a2 += __shfl_xor(a2, 1);
    a2 += __shfl_xor(a2, 2);
    if (q == 0) { SSf[pr] = a3; SSf[16 + pr] = a2; }  // overlay on vvv: same-wave WAR
    if (lane < 4) {
      floatx4 v3 = *(const floatx4*)&SSf[lane * 4];
      floatx4 v2v = *(const floatx4*)&SSf[16 + lane * 4];
      float e3[4], e2v[4], s3 = 0.f, s2v = 0.f;
#pragma unroll
      for (int j = 0; j < 4; ++j) {
        e3[j] = __expf(v3[j]); s3 += e3[j];
        e2v[j] = __expf(v2v[j]); s2v += e2v[j];
      }
      float r3 = __builtin_amdgcn_rcpf(s3), r2 = __builtin_amdgcn_rcpf(s2v);
      floatx4 mm;
#pragma unroll
      for (int j = 0; j < 4; ++j) mm[j] = fmaf(e3[j], r3, e2v[j] * r2);
      *(floatx4*)&SSf[32 + lane * 4] = mm;
    }
  }
  __syncthreads();  // P' + Mm ready

  // ---- P3: diagonal fold P'[a][tb*9+ka] += Mm[ta][tb] (144 lanes) ----
  if (tid < 144) {
    int a = tid >> 2, t2i = tid & 3;
    int ta = (a * 57) >> 9;
    int ka = a - 9 * ta;
    int off = a * 72 + t2i * 9 + ka;
    P1b[off] = f2h(h2f(P1b[off]) + SSf[32 + ta * 4 + t2i]);
  }
  __syncthreads();

  // ---- P5: x6 = P'' @ X3 via MFMA (wave = c-block; B-frags from gathered regs) ----
  {
    half8 xb0 = __builtin_bit_cast(half8, xv0);
    half8 xb1 = __builtin_bit_cast(half8, xv1);
    int c = wid * 16 + colL;
#pragma unroll
    for (int ti = 0; ti < 3; ++ti) {
      floatx4 acc = {0.f, 0.f, 0.f, 0.f};
      int ar = (ti * 16 + colL) * 72 + (kg << 3);
      acc = __builtin_amdgcn_mfma_f32_16x16x32_f16(*(const half8*)&P1b[ar], xb0, acc, 0, 0, 0);
      acc = __builtin_amdgcn_mfma_f32_16x16x32_f16(*(const half8*)&P1b[ar + 32], xb1, acc, 0, 0, 0);
      int r0 = ti * 16 + (kg << 2);
#pragma unroll
      for (int r = 0; r < 4; ++r) {
        int a = r0 + r;
        if (a < 36) X6f[a * 68 + c] = acc[r];
      }
    }
  }
  __syncthreads();

  // ---- P6: exp'd score4 logits expL[a] = exp(<x6[a,:], x6[ctr,:]>) (144 lanes) ----
  if (tid < 144) {
    int a = tid >> 2, q = tid & 3;
    int ctr = ((a * 57) >> 9) * 9 + 4;
    const floatx4* rowA = (const floatx4*)&X6f[a * 68 + q * 16];
    const floatx4* rowC = (const floatx4*)&X6f[ctr * 68 + q * 16];
    float s = 0.f;
#pragma unroll
    for (int j = 0; j < 4; ++j) {
      floatx4 va = rowA[j], vc = rowC[j];
      s = fmaf(va[0], vc[0], s);
      s = fmaf(va[1], vc[1], s);
      s = fmaf(va[2], vc[2], s);
      s = fmaf(va[3], vc[3], s);
    }
    s += __shfl_xor(s, 1);
    s += __shfl_xor(s, 2);
    if (q == 0) L4f[a] = __expf(s);  // pre-exp'd; overlay on mmv (dead)
  }
  __syncthreads();

  // ---- P8: softmax-pool from pre-exp'd weights (t=wid, c=lane) ----
  {
    float den = 0.f, num = 0.f;
#pragma unroll
    for (int k = 0; k < 9; ++k) {
      float e = L4f[wid * 9 + k];
      den += e;
      num = fmaf(X6f[(wid * 9 + k) * 68 + lane], e, num);
    }
    out[((size_t)(tb0 + wid) * 64 + lane) * HW + pix] = num * __builtin_amdgcn_rcpf(den);
  }
}

extern "C" void kernel_launch(void* const* d_in, const int* in_sizes, int n_in,
                              void* d_out, int out_size, void* d_ws, size_t ws_size,
                              hipStream_t stream) {
  const float* x = (const float*)d_in[0];
  const float* w1 = (const float*)d_in[1];
  const float* w2 = (const float*)d_in[2];
  const float* w3 = (const float*)d_in[3];
  float* out = (float*)d_out;

  size_t ysz = (size_t)8 * HW * 64;   // fp16 elements per tensor
  size_t ypitch = ysz + 64;           // +64-elem (128 B) zero sink row
  ushort* Y1 = (ushort*)d_ws;
  ushort* Y2 = Y1 + ypitch;
  ushort* Y3 = Y2 + ypitch;

  conv_mfma_kernel<<<dim3(1536), dim3(256), 0, stream>>>(x, w1, w2, w3, Y1, Y2, Y3);
  attn_kernel<<<dim3(2 * HW), dim3(256), 0, stream>>>(Y1, Y2, Y3, out);
}

// Round 18
// 73.066 us; speedup vs baseline: 1.0889x; 1.0076x over previous
//
#include <hip/hip_runtime.h>

#define HW 6144
#define HH 64
#define WWID 96

typedef __attribute__((ext_vector_type(8))) _Float16 half8;
typedef __attribute__((ext_vector_type(2))) _Float16 half2v;
typedef __attribute__((ext_vector_type(8))) unsigned short ushort8;
typedef __attribute__((ext_vector_type(4))) float floatx4;
typedef __attribute__((ext_vector_type(4))) uint uint4v;
typedef __attribute__((ext_vector_type(4))) int int4v;

static __device__ __forceinline__ ushort f2h(float x) {
  _Float16 h = (_Float16)x;
  return __builtin_bit_cast(ushort, h);
}
static __device__ __forceinline__ float h2f(ushort b) {
  return (float)__builtin_bit_cast(_Float16, b);
}
static __device__ __forceinline__ uint pk2h(float a, float b) {
  return __builtin_bit_cast(uint, __builtin_amdgcn_cvt_pkrtz(a, b));
}
static __device__ __forceinline__ float hdot2(uint a, uint b, float c) {
#if __has_builtin(__builtin_amdgcn_fdot2)
  return __builtin_amdgcn_fdot2(__builtin_bit_cast(half2v, a),
                                __builtin_bit_cast(half2v, b), c, false);
#else
  c = fmaf(h2f((ushort)a), h2f((ushort)b), c);
  return fmaf(h2f((ushort)(a >> 16)), h2f((ushort)(b >> 16)), c);
#endif
}
static __device__ __forceinline__ half2v h2shfl16(half2v v) {
  return __builtin_bit_cast(half2v,
      (uint)__shfl_xor((int)__builtin_bit_cast(uint, v), 16));
}

// ---------------- conv1x1 + relu via MFMA (W fp32 -> frags in-register) ----------------
// Grid 1536 = 8 b x 192 p-tiles(32). Block 0 zeroes the 128-byte OOB sink row of each Y.
__global__ __launch_bounds__(256) void conv_mfma_kernel(
    const float* __restrict__ X, const float* __restrict__ W1,
    const float* __restrict__ W2, const float* __restrict__ W3,
    ushort* __restrict__ Y1, ushort* __restrict__ Y2, ushort* __restrict__ Y3) {
  __shared__ __align__(16) ushort Xt[32 * 72];  // [p][c^], XOR-swizzled fp16
  const int tid = threadIdx.x;
  const int wid = tid >> 6, lane = tid & 63;
  const int b = blockIdx.x / 192;
  const int p0 = (blockIdx.x % 192) * 32;

  if (blockIdx.x == 0 && tid < 96) {  // zero sinks for attn's OOB loads
    int which = tid >> 5, i = tid & 31;
    ushort* Ys = which == 0 ? Y1 : which == 1 ? Y2 : Y3;
    ((uint*)(Ys + (size_t)8 * HW * 64))[i] = 0u;
  }

#pragma unroll
  for (int it = 0; it < 2; ++it) {
    int idx = it * 256 + tid;
    int c = idx >> 3, pq = idx & 7;
    floatx4 v = *(const floatx4*)&X[((size_t)b * 64 + c) * HW + p0 + 4 * pq];
#pragma unroll
    for (int j = 0; j < 4; ++j) {
      int p = 4 * pq + j;
      Xt[p * 72 + (c ^ (p & 56))] = f2h(v[j]);
    }
  }
  __syncthreads();

  const int col = lane & 15, kg = lane >> 4;
  const int ph = wid & 1, mth = wid >> 1;
  const int p = ph * 16 + col;
  half8 b0 = *(const half8*)&Xt[p * 72 + ((kg * 8) ^ (p & 56))];
  half8 b1 = *(const half8*)&Xt[p * 72 + ((kg * 8 + 32) ^ (p & 56))];
  const size_t pixbase = ((size_t)b * HW + p0 + p) * 64;

  for (int s = 0; s < 3; ++s) {
    const float* Wf = (s == 0) ? W1 : (s == 1) ? W2 : W3;
    ushort* Y = (s == 0) ? Y1 : (s == 1) ? Y2 : Y3;
#pragma unroll
    for (int m = 0; m < 2; ++m) {
      int mt = mth * 2 + m;
      const float* wp = &Wf[(mt * 16 + col) * 64 + kg * 8];
      floatx4 w0 = *(const floatx4*)wp;
      floatx4 w1v = *(const floatx4*)(wp + 4);
      floatx4 w2v = *(const floatx4*)(wp + 32);
      floatx4 w3v = *(const floatx4*)(wp + 36);
      uint4v ua, ub;
      ua[0] = pk2h(w0[0], w0[1]);  ua[1] = pk2h(w0[2], w0[3]);
      ua[2] = pk2h(w1v[0], w1v[1]); ua[3] = pk2h(w1v[2], w1v[3]);
      ub[0] = pk2h(w2v[0], w2v[1]); ub[1] = pk2h(w2v[2], w2v[3]);
      ub[2] = pk2h(w3v[0], w3v[1]); ub[3] = pk2h(w3v[2], w3v[3]);
      half8 a0 = __builtin_bit_cast(half8, ua);
      half8 a1 = __builtin_bit_cast(half8, ub);
      floatx4 acc = {0.f, 0.f, 0.f, 0.f};
      acc = __builtin_amdgcn_mfma_f32_16x16x32_f16(a0, b0, acc, 0, 0, 0);
      acc = __builtin_amdgcn_mfma_f32_16x16x32_f16(a1, b1, acc, 0, 0, 0);
      uint2 u;
      u.x = pk2h(fmaxf(acc[0], 0.f), fmaxf(acc[1], 0.f));
      u.y = pk2h(fmaxf(acc[2], 0.f), fmaxf(acc[3], 0.f));
      *(uint2*)&Y[pixbase + mt * 16 + 4 * kg] = u;
    }
  }
}

// ---------------- per-pixel attention stage ----------------
// 12288 blocks x 256. LDS 19328 B -> 8 blocks/CU.
// Unified SMEM carve (M-pad rows of X1b/P1b are READ-ONLY don't-care -> alias next region):
//   [0      .. 2592)  X1b, 36 rows x 72 (A-pad reads rows 36-47 hit X2b real data, finite)
//   [2592   .. 6048)  X2b, 48 rows x 72 (rows 36-47 zeroed: S1 B-pad)
//   [6048   .. 8640)  P1b, 36 rows x 72 (x5 A-pad reads rows 36-47 hit mmv/vvv, finite)
//   [8640   .. 9152)  mmv (2x128 uint), later L4f overlay
//   [9152   .. 9664)  vvv (2x128 uint), later SSf overlay
//   X6f (36 x 68 fp32 = 9792 B) overlays X1b+X2b (12096 B) after P1.
__global__ __launch_bounds__(256, 8) void attn_kernel(
    const ushort* __restrict__ Y1, const ushort* __restrict__ Y2,
    const ushort* __restrict__ Y3, float* __restrict__ out) {
  __shared__ __align__(16) ushort SMEM[9664];

  ushort* X1b = SMEM;
  ushort* X2b = SMEM + 2592;
  ushort* P1b = SMEM + 6048;
  uint* mmv = (uint*)(SMEM + 8640);   // [s*128 + t*32 + cp]
  uint* vvv = (uint*)(SMEM + 9152);
  float* X6f = (float*)SMEM;          // valid after X1b/X2b dead
  float* SSf = (float*)vvv;           // [0..15]=SS3 [16..31]=SS2 [32..47]=Mm
  float* L4f = (float*)mmv;           // [0..35] exp(score4 logits), valid P6..P8

  const int tid = threadIdx.x;
  const int wid = tid >> 6;
  const int lane = tid & 63;
  const int bid0 = blockIdx.x;
  const int bid = (bid0 & 7) * (12288 >> 3) + (bid0 >> 3);  // XCD-bijective
  const int pix = bid % HW;
  const int nn = bid / HW;
  const int h = pix / WWID, w = pix - h * WWID;
  const int tb0 = nn * 4;
  const int SINKE = 8 * HW * 64;  // element offset of zero sink row in each Y

  // ---- P0: tap loads (sink-redirected, unconditional) + packed-fp16 stats; offv; pads ----
  {
    const int s = wid >> 1;
    const int t = (wid & 1) * 2 + (lane >> 5);
    const int kh = (lane >> 4) & 1;
    const int cq = lane & 15;
    const ushort* Ysrc = s ? Y2 : Y1;
    const int base = (tb0 + t) * HW + pix;
    half2v s1a = {0, 0}, s1b = {0, 0}, s2a = {0, 0}, s2b = {0, 0};
#pragma unroll
    for (int i = 0; i < 5; ++i) {
      int k = 2 * i + kh;
      if (k < 9) {
        int k3 = (k * 11) >> 5;
        int dh = k3 - 1, dw = k - 3 * k3 - 1;
        bool valid = ((unsigned)(h + dh) < HH) & ((unsigned)(w + dw) < WWID);
        int off = valid ? (base + dh * WWID + dw) * 64 : SINKE;
        uint2 uv = *(const uint2*)&Ysrc[off + 4 * cq];
        *(uint2*)&SMEM[s * 2592 + (t * 9 + k) * 72 + 4 * cq] = uv;
        half2v va = __builtin_bit_cast(half2v, uv.x);
        half2v vb = __builtin_bit_cast(half2v, uv.y);
        s1a += va; s2a += va * va;
        s1b += vb; s2b += vb * vb;
      }
    }
    s1a += h2shfl16(s1a);
    s1b += h2shfl16(s1b);
    s2a += h2shfl16(s2a);
    s2b += h2shfl16(s2b);
    if (kh == 0) {
      float s1f[4] = {(float)s1a[0], (float)s1a[1], (float)s1b[0], (float)s1b[1]};
      float s2f[4] = {(float)s2a[0], (float)s2a[1], (float)s2b[0], (float)s2b[1]};
      float mf[4], vf[4];
#pragma unroll
      for (int j = 0; j < 4; ++j) {
        mf[j] = s1f[j] * (1.f / 9.f);
        vf[j] = (s2f[j] - s1f[j] * s1f[j] * (1.f / 9.f)) * 0.125f;
      }
      mmv[s * 128 + t * 32 + 2 * cq] = pk2h(mf[0], mf[1]);
      mmv[s * 128 + t * 32 + 2 * cq + 1] = pk2h(mf[2], mf[3]);
      vvv[s * 128 + t * 32 + 2 * cq] = pk2h(vf[0], vf[1]);
      vvv[s * 128 + t * 32 + 2 * cq + 1] = pk2h(vf[2], vf[3]);
    }
  }
  if (tid < 64) {  // offv: BYTE offset of (t,tap) pixel row in Y3 (sink if OOB/pad)
    int b = tid;
    int o = SINKE * 2;
    if (b < 36) {
      int t = (b * 57) >> 9;
      int k = b - 9 * t;
      int k3 = (k * 11) >> 5;
      int hh = h + k3 - 1, ww = w + (k - 3 * k3) - 1;
      if ((unsigned)hh < HH && (unsigned)ww < WWID)
        o = ((tb0 + t) * HW + hh * WWID + ww) * 128;
    }
    ((int*)&P1b[(b >> 2) * 72 + 64])[b & 3] = o;
  }
  for (int i = tid; i < 288; i += 256) {  // P1b K-pad cols 48..63, rows 0..35 (finite)
    int r = i >> 3, u = i & 7;
    *(uint*)&P1b[r * 72 + 48 + 2 * u] = 0u;
  }
  for (int i = tid; i < 192; i += 256) {  // X2b pad rows 36..47 (S1 B-pad must be 0)
    int r = i >> 4, cq = i & 15;
    uint2 z; z.x = 0u; z.y = 0u;
    *(uint2*)&X2b[(36 + r) * 72 + 4 * cq] = z;
  }
  __syncthreads();

  // ---- X3 B-frags: int4-packed offsets + unconditional gather (drains under P1) ----
  const int colL = lane & 15, kg = lane >> 4;
  ushort8 xv0, xv1;
  {
    const int c2 = (wid * 16 + colL) * 2;
    const char* Y3b = (const char*)Y3;
    int4v oa = *(const int4v*)&P1b[(kg * 2) * 72 + 64];
    int4v ob = *(const int4v*)&P1b[(kg * 2 + 1) * 72 + 64];
    int4v oc = *(const int4v*)&P1b[(kg * 2 + 8) * 72 + 64];
    int4v od = *(const int4v*)&P1b[(kg * 2 + 9) * 72 + 64];
#pragma unroll
    for (int j = 0; j < 4; ++j) {
      xv0[j] = *(const ushort*)(Y3b + (oa[j] + c2));
      xv0[4 + j] = *(const ushort*)(Y3b + (ob[j] + c2));
      xv1[j] = *(const ushort*)(Y3b + (oc[j] + c2));
      xv1[4 + j] = *(const ushort*)(Y3b + (od[j] + c2));
    }
  }

  // ---- P1: S1 MFMA + no-max softmax + P' (waves 0-2) || fdot2 dots + Mm (wave 3) ----
  if (wid < 3) {
    floatx4 ac0 = {0.f, 0.f, 0.f, 0.f}, ac1 = ac0, ac2 = ac0;
    int ar = (wid * 16 + colL) * 72 + (kg << 3);
    half8 a0 = *(const half8*)&X1b[ar];
    half8 a1 = *(const half8*)&X1b[ar + 32];
    int brb = colL * 72 + (kg << 3);
    ac0 = __builtin_amdgcn_mfma_f32_16x16x32_f16(a0, *(const half8*)&X2b[brb], ac0, 0, 0, 0);
    ac0 = __builtin_amdgcn_mfma_f32_16x16x32_f16(a1, *(const half8*)&X2b[brb + 32], ac0, 0, 0, 0);
    ac1 = __builtin_amdgcn_mfma_f32_16x16x32_f16(a0, *(const half8*)&X2b[brb + 16 * 72], ac1, 0, 0, 0);
    ac1 = __builtin_amdgcn_mfma_f32_16x16x32_f16(a1, *(const half8*)&X2b[brb + 16 * 72 + 32], ac1, 0, 0, 0);
    ac2 = __builtin_amdgcn_mfma_f32_16x16x32_f16(a0, *(const half8*)&X2b[brb + 32 * 72], ac2, 0, 0, 0);
    ac2 = __builtin_amdgcn_mfma_f32_16x16x32_f16(a1, *(const half8*)&X2b[brb + 32 * 72 + 32], ac2, 0, 0, 0);

    bool v2 = (colL < 4);
#pragma unroll
    for (int r = 0; r < 4; ++r) {
      float e0 = __expf(ac0[r]);
      float e1 = __expf(ac1[r]);
      float e2 = __expf(ac2[r]);
      float sm = e0 + e1 + (v2 ? e2 : 0.f);
#pragma unroll
      for (int d = 1; d < 16; d <<= 1) sm += __shfl_xor(sm, d);
      float rs = __builtin_amdgcn_rcpf(sm);
      int row = wid * 16 + 4 * kg + r;
      if (row < 36) {  // rows 36-47 are discarded M-pad; P1b has no storage for them
        int ro = row * 72 + colL;
        P1b[ro] = f2h(e0 * rs);
        P1b[ro + 16] = f2h(e1 * rs);
        P1b[ro + 32] = f2h(e2 * rs);
      }
    }
  } else {
    int pr = lane >> 2, q = lane & 3;
    int t1 = pr >> 2, t2 = pr & 3;
    float a3 = 0.f, a2 = 0.f;
#pragma unroll
    for (int j = 0; j < 8; ++j) {
      int cp = q * 8 + j;
      a3 = hdot2(mmv[t1 * 32 + cp], mmv[128 + t2 * 32 + cp], a3);
      a2 = hdot2(vvv[t1 * 32 + cp], vvv[128 + t2 * 32 + cp], a2);
    }
    a3 += __shfl_xor(a3, 1);
    a3 += __shfl_xor(a3, 2);
    a2 += __shfl_xor(a2, 1);
    a2 += __shfl_xor(a2, 2);
    if (q == 0) { SSf[pr] = a3; SSf[16 + pr] = a2; }  // overlay on vvv: same-wave WAR
    if (lane < 4) {
      floatx4 v3 = *(const floatx4*)&SSf[lane * 4];
      floatx4 v2v = *(const floatx4*)&SSf[16 + lane * 4];
      float e3[4], e2v[4], s3 = 0.f, s2v = 0.f;
#pragma unroll
      for (int j = 0; j < 4; ++j) {
        e3[j] = __expf(v3[j]); s3 += e3[j];
        e2v[j] = __expf(v2v[j]); s2v += e2v[j];
      }
      float r3 = __builtin_amdgcn_rcpf(s3), r2 = __builtin_amdgcn_rcpf(s2v);
      floatx4 mm;
#pragma unroll
      for (int j = 0; j < 4; ++j) mm[j] = fmaf(e3[j], r3, e2v[j] * r2);
      *(floatx4*)&SSf[32 + lane * 4] = mm;
    }
  }
  __syncthreads();  // P' + Mm ready

  // ---- P3: diagonal fold P'[a][tb*9+ka] += Mm[ta][tb] (144 lanes) ----
  if (tid < 144) {
    int a = tid >> 2, t2i = tid & 3;
    int ta = (a * 57) >> 9;
    int ka = a - 9 * ta;
    int off = a * 72 + t2i * 9 + ka;
    P1b[off] = f2h(h2f(P1b[off]) + SSf[32 + ta * 4 + t2i]);
  }
  __syncthreads();

  // ---- P5: x6 = P'' @ X3 via MFMA (wave = c-block; B-frags from gathered regs) ----
  // A-operand rows 36-47 read past P1b into mmv/vvv (finite don't-care; C rows masked).
  {
    half8 xb0 = __builtin_bit_cast(half8, xv0);
    half8 xb1 = __builtin_bit_cast(half8, xv1);
    int c = wid * 16 + colL;
#pragma unroll
    for (int ti = 0; ti < 3; ++ti) {
      floatx4 acc = {0.f, 0.f, 0.f, 0.f};
      int ar = (ti * 16 + colL) * 72 + (kg << 3);
      acc = __builtin_amdgcn_mfma_f32_16x16x32_f16(*(const half8*)&P1b[ar], xb0, acc, 0, 0, 0);
      acc = __builtin_amdgcn_mfma_f32_16x16x32_f16(*(const half8*)&P1b[ar + 32], xb1, acc, 0, 0, 0);
      int r0 = ti * 16 + (kg << 2);
#pragma unroll
      for (int r = 0; r < 4; ++r) {
        int a = r0 + r;
        if (a < 36) X6f[a * 68 + c] = acc[r];
      }
    }
  }
  __syncthreads();

  // ---- P6: exp'd score4 logits expL[a] = exp(<x6[a,:], x6[ctr,:]>) (144 lanes) ----
  if (tid < 144) {
    int a = tid >> 2, q = tid & 3;
    int ctr = ((a * 57) >> 9) * 9 + 4;
    const floatx4* rowA = (const floatx4*)&X6f[a * 68 + q * 16];
    const floatx4* rowC = (const floatx4*)&X6f[ctr * 68 + q * 16];
    float s = 0.f;
#pragma unroll
    for (int j = 0; j < 4; ++j) {
      floatx4 va = rowA[j], vc = rowC[j];
      s = fmaf(va[0], vc[0], s);
      s = fmaf(va[1], vc[1], s);
      s = fmaf(va[2], vc[2], s);
      s = fmaf(va[3], vc[3], s);
    }
    s += __shfl_xor(s, 1);
    s += __shfl_xor(s, 2);
    if (q == 0) L4f[a] = __expf(s);  // pre-exp'd; overlay on mmv (dead)
  }
  __syncthreads();

  // ---- P8: softmax-pool from pre-exp'd weights (t=wid, c=lane) ----
  {
    float den = 0.f, num = 0.f;
#pragma unroll
    for (int k = 0; k < 9; ++k) {
      float e = L4f[wid * 9 + k];
      den += e;
      num = fmaf(X6f[(wid * 9 + k) * 68 + lane], e, num);
    }
    out[((size_t)(tb0 + wid) * 64 + lane) * HW + pix] = num * __builtin_amdgcn_rcpf(den);
  }
}

extern "C" void kernel_launch(void* const* d_in, const int* in_sizes, int n_in,
                              void* d_out, int out_size, void* d_ws, size_t ws_size,
                              hipStream_t stream) {
  const float* x = (const float*)d_in[0];
  const float* w1 = (const float*)d_in[1];
  const float* w2 = (const float*)d_in[2];
  const float* w3 = (const float*)d_in[3];
  float* out = (float*)d_out;

  size_t ysz = (size_t)8 * HW * 64;   // fp16 elements per tensor
  size_t ypitch = ysz + 64;           // +64-elem (128 B) zero sink row
  ushort* Y1 = (ushort*)d_ws;
  ushort* Y2 = Y1 + ypitch;
  ushort* Y3 = Y2 + ypitch;

  conv_mfma_kernel<<<dim3(1536), dim3(256), 0, stream>>>(x, w1, w2, w3, Y1, Y2, Y3);
  attn_kernel<<<dim3(2 * HW), dim3(256), 0, stream>>>(Y1, Y2, Y3, out);
}

// Round 19
// 72.959 us; speedup vs baseline: 1.0905x; 1.0015x over previous
//
#include <hip/hip_runtime.h>

#define HW 6144
#define HH 64
#define WWID 96

typedef __attribute__((ext_vector_type(8))) _Float16 half8;
typedef __attribute__((ext_vector_type(2))) _Float16 half2v;
typedef __attribute__((ext_vector_type(8))) unsigned short ushort8;
typedef __attribute__((ext_vector_type(4))) float floatx4;
typedef __attribute__((ext_vector_type(4))) uint uint4v;
typedef __attribute__((ext_vector_type(4))) int int4v;

static __device__ __forceinline__ ushort f2h(float x) {
  _Float16 h = (_Float16)x;
  return __builtin_bit_cast(ushort, h);
}
static __device__ __forceinline__ float h2f(ushort b) {
  return (float)__builtin_bit_cast(_Float16, b);
}
static __device__ __forceinline__ uint pk2h(float a, float b) {
  return __builtin_bit_cast(uint, __builtin_amdgcn_cvt_pkrtz(a, b));
}
static __device__ __forceinline__ float hdot2(uint a, uint b, float c) {
#if __has_builtin(__builtin_amdgcn_fdot2)
  return __builtin_amdgcn_fdot2(__builtin_bit_cast(half2v, a),
                                __builtin_bit_cast(half2v, b), c, false);
#else
  c = fmaf(h2f((ushort)a), h2f((ushort)b), c);
  return fmaf(h2f((ushort)(a >> 16)), h2f((ushort)(b >> 16)), c);
#endif
}
static __device__ __forceinline__ half2v h2shfl16(half2v v) {
  return __builtin_bit_cast(half2v,
      (uint)__shfl_xor((int)__builtin_bit_cast(uint, v), 16));
}

// ---------------- conv1x1 + relu via MFMA (W fp32 -> frags in-register) ----------------
// Grid 1536 = 8 b x 192 p-tiles(32). Block 0 zeroes the 128-byte OOB sink row of each Y.
// Xt staging: thread owns a c-pair x 4 pixels -> packed uint ds_writes (swizzle keeps
// even-c pairs adjacent since (p&56) has low 3 bits clear).
__global__ __launch_bounds__(256) void conv_mfma_kernel(
    const float* __restrict__ X, const float* __restrict__ W1,
    const float* __restrict__ W2, const float* __restrict__ W3,
    ushort* __restrict__ Y1, ushort* __restrict__ Y2, ushort* __restrict__ Y3) {
  __shared__ __align__(16) ushort Xt[32 * 72];  // [p][c^], XOR-swizzled fp16
  const int tid = threadIdx.x;
  const int wid = tid >> 6, lane = tid & 63;
  const int b = blockIdx.x / 192;
  const int p0 = (blockIdx.x % 192) * 32;

  if (blockIdx.x == 0 && tid < 96) {  // zero sinks for attn's OOB loads
    int which = tid >> 5, i = tid & 31;
    ushort* Ys = which == 0 ? Y1 : which == 1 ? Y2 : Y3;
    ((uint*)(Ys + (size_t)8 * HW * 64))[i] = 0u;
  }

  {
    const int c0 = (tid >> 3) * 2;   // even channel of the pair
    const int pq = tid & 7;          // pixel quad
    const float* xb = &X[((size_t)b * 64 + c0) * HW + p0 + 4 * pq];
    floatx4 v0 = *(const floatx4*)xb;
    floatx4 v1 = *(const floatx4*)(xb + HW);
#pragma unroll
    for (int j = 0; j < 4; ++j) {
      int p = 4 * pq + j;
      *(uint*)&Xt[p * 72 + (c0 ^ (p & 56))] = pk2h(v0[j], v1[j]);
    }
  }
  __syncthreads();

  const int col = lane & 15, kg = lane >> 4;
  const int ph = wid & 1, mth = wid >> 1;
  const int p = ph * 16 + col;
  half8 b0 = *(const half8*)&Xt[p * 72 + ((kg * 8) ^ (p & 56))];
  half8 b1 = *(const half8*)&Xt[p * 72 + ((kg * 8 + 32) ^ (p & 56))];
  const size_t pixbase = ((size_t)b * HW + p0 + p) * 64;

  for (int s = 0; s < 3; ++s) {
    const float* Wf = (s == 0) ? W1 : (s == 1) ? W2 : W3;
    ushort* Y = (s == 0) ? Y1 : (s == 1) ? Y2 : Y3;
#pragma unroll
    for (int m = 0; m < 2; ++m) {
      int mt = mth * 2 + m;
      const float* wp = &Wf[(mt * 16 + col) * 64 + kg * 8];
      floatx4 w0 = *(const floatx4*)wp;
      floatx4 w1v = *(const floatx4*)(wp + 4);
      floatx4 w2v = *(const floatx4*)(wp + 32);
      floatx4 w3v = *(const floatx4*)(wp + 36);
      uint4v ua, ub;
      ua[0] = pk2h(w0[0], w0[1]);  ua[1] = pk2h(w0[2], w0[3]);
      ua[2] = pk2h(w1v[0], w1v[1]); ua[3] = pk2h(w1v[2], w1v[3]);
      ub[0] = pk2h(w2v[0], w2v[1]); ub[1] = pk2h(w2v[2], w2v[3]);
      ub[2] = pk2h(w3v[0], w3v[1]); ub[3] = pk2h(w3v[2], w3v[3]);
      half8 a0 = __builtin_bit_cast(half8, ua);
      half8 a1 = __builtin_bit_cast(half8, ub);
      floatx4 acc = {0.f, 0.f, 0.f, 0.f};
      acc = __builtin_amdgcn_mfma_f32_16x16x32_f16(a0, b0, acc, 0, 0, 0);
      acc = __builtin_amdgcn_mfma_f32_16x16x32_f16(a1, b1, acc, 0, 0, 0);
      uint2 u;
      u.x = pk2h(fmaxf(acc[0], 0.f), fmaxf(acc[1], 0.f));
      u.y = pk2h(fmaxf(acc[2], 0.f), fmaxf(acc[3], 0.f));
      *(uint2*)&Y[pixbase + mt * 16 + 4 * kg] = u;
    }
  }
}

// ---------------- per-pixel attention stage ----------------
// 12288 blocks x 256. LDS 19328 B -> 8 blocks/CU. (Byte-identical to r18.)
__global__ __launch_bounds__(256, 8) void attn_kernel(
    const ushort* __restrict__ Y1, const ushort* __restrict__ Y2,
    const ushort* __restrict__ Y3, float* __restrict__ out) {
  __shared__ __align__(16) ushort SMEM[9664];

  ushort* X1b = SMEM;
  ushort* X2b = SMEM + 2592;
  ushort* P1b = SMEM + 6048;
  uint* mmv = (uint*)(SMEM + 8640);   // [s*128 + t*32 + cp]
  uint* vvv = (uint*)(SMEM + 9152);
  float* X6f = (float*)SMEM;          // valid after X1b/X2b dead
  float* SSf = (float*)vvv;           // [0..15]=SS3 [16..31]=SS2 [32..47]=Mm
  float* L4f = (float*)mmv;           // [0..35] exp(score4 logits), valid P6..P8

  const int tid = threadIdx.x;
  const int wid = tid >> 6;
  const int lane = tid & 63;
  const int bid0 = blockIdx.x;
  const int bid = (bid0 & 7) * (12288 >> 3) + (bid0 >> 3);  // XCD-bijective
  const int pix = bid % HW;
  const int nn = bid / HW;
  const int h = pix / WWID, w = pix - h * WWID;
  const int tb0 = nn * 4;
  const int SINKE = 8 * HW * 64;  // element offset of zero sink row in each Y

  // ---- P0: tap loads (sink-redirected, unconditional) + packed-fp16 stats; offv; pads ----
  {
    const int s = wid >> 1;
    const int t = (wid & 1) * 2 + (lane >> 5);
    const int kh = (lane >> 4) & 1;
    const int cq = lane & 15;
    const ushort* Ysrc = s ? Y2 : Y1;
    const int base = (tb0 + t) * HW + pix;
    half2v s1a = {0, 0}, s1b = {0, 0}, s2a = {0, 0}, s2b = {0, 0};
#pragma unroll
    for (int i = 0; i < 5; ++i) {
      int k = 2 * i + kh;
      if (k < 9) {
        int k3 = (k * 11) >> 5;
        int dh = k3 - 1, dw = k - 3 * k3 - 1;
        bool valid = ((unsigned)(h + dh) < HH) & ((unsigned)(w + dw) < WWID);
        int off = valid ? (base + dh * WWID + dw) * 64 : SINKE;
        uint2 uv = *(const uint2*)&Ysrc[off + 4 * cq];
        *(uint2*)&SMEM[s * 2592 + (t * 9 + k) * 72 + 4 * cq] = uv;
        half2v va = __builtin_bit_cast(half2v, uv.x);
        half2v vb = __builtin_bit_cast(half2v, uv.y);
        s1a += va; s2a += va * va;
        s1b += vb; s2b += vb * vb;
      }
    }
    s1a += h2shfl16(s1a);
    s1b += h2shfl16(s1b);
    s2a += h2shfl16(s2a);
    s2b += h2shfl16(s2b);
    if (kh == 0) {
      float s1f[4] = {(float)s1a[0], (float)s1a[1], (float)s1b[0], (float)s1b[1]};
      float s2f[4] = {(float)s2a[0], (float)s2a[1], (float)s2b[0], (float)s2b[1]};
      float mf[4], vf[4];
#pragma unroll
      for (int j = 0; j < 4; ++j) {
        mf[j] = s1f[j] * (1.f / 9.f);
        vf[j] = (s2f[j] - s1f[j] * s1f[j] * (1.f / 9.f)) * 0.125f;
      }
      mmv[s * 128 + t * 32 + 2 * cq] = pk2h(mf[0], mf[1]);
      mmv[s * 128 + t * 32 + 2 * cq + 1] = pk2h(mf[2], mf[3]);
      vvv[s * 128 + t * 32 + 2 * cq] = pk2h(vf[0], vf[1]);
      vvv[s * 128 + t * 32 + 2 * cq + 1] = pk2h(vf[2], vf[3]);
    }
  }
  if (tid < 64) {  // offv: BYTE offset of (t,tap) pixel row in Y3 (sink if OOB/pad)
    int b = tid;
    int o = SINKE * 2;
    if (b < 36) {
      int t = (b * 57) >> 9;
      int k = b - 9 * t;
      int k3 = (k * 11) >> 5;
      int hh = h + k3 - 1, ww = w + (k - 3 * k3) - 1;
      if ((unsigned)hh < HH && (unsigned)ww < WWID)
        o = ((tb0 + t) * HW + hh * WWID + ww) * 128;
    }
    ((int*)&P1b[(b >> 2) * 72 + 64])[b & 3] = o;
  }
  for (int i = tid; i < 288; i += 256) {  // P1b K-pad cols 48..63, rows 0..35 (finite)
    int r = i >> 3, u = i & 7;
    *(uint*)&P1b[r * 72 + 48 + 2 * u] = 0u;
  }
  for (int i = tid; i < 192; i += 256) {  // X2b pad rows 36..47 (S1 B-pad must be 0)
    int r = i >> 4, cq = i & 15;
    uint2 z; z.x = 0u; z.y = 0u;
    *(uint2*)&X2b[(36 + r) * 72 + 4 * cq] = z;
  }
  __syncthreads();

  // ---- X3 B-frags: int4-packed offsets + unconditional gather (drains under P1) ----
  const int colL = lane & 15, kg = lane >> 4;
  ushort8 xv0, xv1;
  {
    const int c2 = (wid * 16 + colL) * 2;
    const char* Y3b = (const char*)Y3;
    int4v oa = *(const int4v*)&P1b[(kg * 2) * 72 + 64];
    int4v ob = *(const int4v*)&P1b[(kg * 2 + 1) * 72 + 64];
    int4v oc = *(const int4v*)&P1b[(kg * 2 + 8) * 72 + 64];
    int4v od = *(const int4v*)&P1b[(kg * 2 + 9) * 72 + 64];
#pragma unroll
    for (int j = 0; j < 4; ++j) {
      xv0[j] = *(const ushort*)(Y3b + (oa[j] + c2));
      xv0[4 + j] = *(const ushort*)(Y3b + (ob[j] + c2));
      xv1[j] = *(const ushort*)(Y3b + (oc[j] + c2));
      xv1[4 + j] = *(const ushort*)(Y3b + (od[j] + c2));
    }
  }

  // ---- P1: S1 MFMA + no-max softmax + P' (waves 0-2) || fdot2 dots + Mm (wave 3) ----
  if (wid < 3) {
    floatx4 ac0 = {0.f, 0.f, 0.f, 0.f}, ac1 = ac0, ac2 = ac0;
    int ar = (wid * 16 + colL) * 72 + (kg << 3);
    half8 a0 = *(const half8*)&X1b[ar];
    half8 a1 = *(const half8*)&X1b[ar + 32];
    int brb = colL * 72 + (kg << 3);
    ac0 = __builtin_amdgcn_mfma_f32_16x16x32_f16(a0, *(const half8*)&X2b[brb], ac0, 0, 0, 0);
    ac0 = __builtin_amdgcn_mfma_f32_16x16x32_f16(a1, *(const half8*)&X2b[brb + 32], ac0, 0, 0, 0);
    ac1 = __builtin_amdgcn_mfma_f32_16x16x32_f16(a0, *(const half8*)&X2b[brb + 16 * 72], ac1, 0, 0, 0);
    ac1 = __builtin_amdgcn_mfma_f32_16x16x32_f16(a1, *(const half8*)&X2b[brb + 16 * 72 + 32], ac1, 0, 0, 0);
    ac2 = __builtin_amdgcn_mfma_f32_16x16x32_f16(a0, *(const half8*)&X2b[brb + 32 * 72], ac2, 0, 0, 0);
    ac2 = __builtin_amdgcn_mfma_f32_16x16x32_f16(a1, *(const half8*)&X2b[brb + 32 * 72 + 32], ac2, 0, 0, 0);

    bool v2 = (colL < 4);
#pragma unroll
    for (int r = 0; r < 4; ++r) {
      float e0 = __expf(ac0[r]);
      float e1 = __expf(ac1[r]);
      float e2 = __expf(ac2[r]);
      float sm = e0 + e1 + (v2 ? e2 : 0.f);
#pragma unroll
      for (int d = 1; d < 16; d <<= 1) sm += __shfl_xor(sm, d);
      float rs = __builtin_amdgcn_rcpf(sm);
      int row = wid * 16 + 4 * kg + r;
      if (row < 36) {  // rows 36-47 are discarded M-pad; P1b has no storage for them
        int ro = row * 72 + colL;
        P1b[ro] = f2h(e0 * rs);
        P1b[ro + 16] = f2h(e1 * rs);
        P1b[ro + 32] = f2h(e2 * rs);
      }
    }
  } else {
    int pr = lane >> 2, q = lane & 3;
    int t1 = pr >> 2, t2 = pr & 3;
    float a3 = 0.f, a2 = 0.f;
#pragma unroll
    for (int j = 0; j < 8; ++j) {
      int cp = q * 8 + j;
      a3 = hdot2(mmv[t1 * 32 + cp], mmv[128 + t2 * 32 + cp], a3);
      a2 = hdot2(vvv[t1 * 32 + cp], vvv[128 + t2 * 32 + cp], a2);
    }
    a3 += __shfl_xor(a3, 1);
    a3 += __shfl_xor(a3, 2);
    a2 += __shfl_xor(a2, 1);
    a2 += __shfl_xor(a2, 2);
    if (q == 0) { SSf[pr] = a3; SSf[16 + pr] = a2; }  // overlay on vvv: same-wave WAR
    if (lane < 4) {
      floatx4 v3 = *(const floatx4*)&SSf[lane * 4];
      floatx4 v2v = *(const floatx4*)&SSf[16 + lane * 4];
      float e3[4], e2v[4], s3 = 0.f, s2v = 0.f;
#pragma unroll
      for (int j = 0; j < 4; ++j) {
        e3[j] = __expf(v3[j]); s3 += e3[j];
        e2v[j] = __expf(v2v[j]); s2v += e2v[j];
      }
      float r3 = __builtin_amdgcn_rcpf(s3), r2 = __builtin_amdgcn_rcpf(s2v);
      floatx4 mm;
#pragma unroll
      for (int j = 0; j < 4; ++j) mm[j] = fmaf(e3[j], r3, e2v[j] * r2);
      *(floatx4*)&SSf[32 + lane * 4] = mm;
    }
  }
  __syncthreads();  // P' + Mm ready

  // ---- P3: diagonal fold P'[a][tb*9+ka] += Mm[ta][tb] (144 lanes) ----
  if (tid < 144) {
    int a = tid >> 2, t2i = tid & 3;
    int ta = (a * 57) >> 9;
    int ka = a - 9 * ta;
    int off = a * 72 + t2i * 9 + ka;
    P1b[off] = f2h(h2f(P1b[off]) + SSf[32 + ta * 4 + t2i]);
  }
  __syncthreads();

  // ---- P5: x6 = P'' @ X3 via MFMA (wave = c-block; B-frags from gathered regs) ----
  // A-operand rows 36-47 read past P1b into mmv/vvv (finite don't-care; C rows masked).
  {
    half8 xb0 = __builtin_bit_cast(half8, xv0);
    half8 xb1 = __builtin_bit_cast(half8, xv1);
    int c = wid * 16 + colL;
#pragma unroll
    for (int ti = 0; ti < 3; ++ti) {
      floatx4 acc = {0.f, 0.f, 0.f, 0.f};
      int ar = (ti * 16 + colL) * 72 + (kg << 3);
      acc = __builtin_amdgcn_mfma_f32_16x16x32_f16(*(const half8*)&P1b[ar], xb0, acc, 0, 0, 0);
      acc = __builtin_amdgcn_mfma_f32_16x16x32_f16(*(const half8*)&P1b[ar + 32], xb1, acc, 0, 0, 0);
      int r0 = ti * 16 + (kg << 2);
#pragma unroll
      for (int r = 0; r < 4; ++r) {
        int a = r0 + r;
        if (a < 36) X6f[a * 68 + c] = acc[r];
      }
    }
  }
  __syncthreads();

  // ---- P6: exp'd score4 logits expL[a] = exp(<x6[a,:], x6[ctr,:]>) (144 lanes) ----
  if (tid < 144) {
    int a = tid >> 2, q = tid & 3;
    int ctr = ((a * 57) >> 9) * 9 + 4;
    const floatx4* rowA = (const floatx4*)&X6f[a * 68 + q * 16];
    const floatx4* rowC = (const floatx4*)&X6f[ctr * 68 + q * 16];
    float s = 0.f;
#pragma unroll
    for (int j = 0; j < 4; ++j) {
      floatx4 va = rowA[j], vc = rowC[j];
      s = fmaf(va[0], vc[0], s);
      s = fmaf(va[1], vc[1], s);
      s = fmaf(va[2], vc[2], s);
      s = fmaf(va[3], vc[3], s);
    }
    s += __shfl_xor(s, 1);
    s += __shfl_xor(s, 2);
    if (q == 0) L4f[a] = __expf(s);  // pre-exp'd; overlay on mmv (dead)
  }
  __syncthreads();

  // ---- P8: softmax-pool from pre-exp'd weights (t=wid, c=lane) ----
  {
    float den = 0.f, num = 0.f;
#pragma unroll
    for (int k = 0; k < 9; ++k) {
      float e = L4f[wid * 9 + k];
      den += e;
      num = fmaf(X6f[(wid * 9 + k) * 68 + lane], e, num);
    }
    out[((size_t)(tb0 + wid) * 64 + lane) * HW + pix] = num * __builtin_amdgcn_rcpf(den);
  }
}

extern "C" void kernel_launch(void* const* d_in, const int* in_sizes, int n_in,
                              void* d_out, int out_size, void* d_ws, size_t ws_size,
                              hipStream_t stream) {
  const float* x = (const float*)d_in[0];
  const float* w1 = (const float*)d_in[1];
  const float* w2 = (const float*)d_in[2];
  const float* w3 = (const float*)d_in[3];
  float* out = (float*)d_out;

  size_t ysz = (size_t)8 * HW * 64;   // fp16 elements per tensor
  size_t ypitch = ysz + 64;           // +64-elem (128 B) zero sink row
  ushort* Y1 = (ushort*)d_ws;
  ushort* Y2 = Y1 + ypitch;
  ushort* Y3 = Y2 + ypitch;

  conv_mfma_kernel<<<dim3(1536), dim3(256), 0, stream>>>(x, w1, w2, w3, Y1, Y2, Y3);
  attn_kernel<<<dim3(2 * HW), dim3(256), 0, stream>>>(Y1, Y2, Y3, out);
}